// Round 9
// baseline (90.502 us; speedup 1.0000x reference)
//
#include <hip/hip_runtime.h>

// ---------- types ----------
typedef __attribute__((ext_vector_type(8))) short short8;     // 8 bf16 (4 VGPRs)
typedef __attribute__((ext_vector_type(4))) float floatx4;    // MFMA C/D
typedef __attribute__((ext_vector_type(4))) unsigned int uintx4;

// ---------- fp32 -> packed bf16x2 (RNE) ----------
#if __has_builtin(__builtin_amdgcn_cvt_pk_bf16_f32)
typedef __attribute__((ext_vector_type(2))) __bf16 bf16x2;
__device__ __forceinline__ unsigned int pk_bf16(float a, float b) {
  bf16x2 v = __builtin_amdgcn_cvt_pk_bf16_f32(a, b);
  return __builtin_bit_cast(unsigned int, v);
}
#else
__device__ __forceinline__ unsigned int bf16_1(float f) {
  unsigned int u = __builtin_bit_cast(unsigned int, f);
  return (u + 0x7fffu + ((u >> 16) & 1u)) >> 16;
}
__device__ __forceinline__ unsigned int pk_bf16(float a, float b) {
  return bf16_1(a) | (bf16_1(b) << 16);
}
#endif

// Fragment conventions (verified rounds 0-8, absmax 3.9e-3):
//   A-frag (16x16x32): lane(ln,quad) holds A[m=ln][k=quad*8+j], j=0..7
//   B-frag:            lane(ln,quad) holds B[n=ln][k=quad*8+j]  (B[k][n]=W[c][r][k], n=r*8+c)
//   C/D:               col=ln, row=quad*4+reg
// Bprep frag id: Fb = ((mod*8 + h)*24 + ks)*4 + nt, n16 = h*4+nt; frag = 64 lanes x 16B.
//
// LEDGER OF DEAD ENDS (do not revisit without new evidence):
// * STORE GEOMETRY IS LOAD-BEARING: scalar dword stores, 16 consecutive
//   dwords per 16-lane group x 4 rows per instr -> WRITE_SIZE 98.5 MB (1.0x).
//   float4 @32B-stride = 1.5x; LDS-bounced dense dwordx4 = 3.0x (288 MiB
//   exact, NT or not); extra writes also evict X from L3 (FETCH 81->127 MB).
// * NONTEMPORAL hints: loads defeat L3 residency of X, stores amplify writes.
// * PERMUTED-B (n'=c*64+r) + direct stores: silent transpose (round-6
//   absmax 1.55); shuffle-free squash needs the 3.0x bounce -> net loss.
// * 3-DEEP REGISTER BUFFERING: regs > launch-bounds cap -> scratch spills;
//   signature is WRITE_SIZE 612 MB / FETCH 211 MB / 2.4x dur (round 7).
// ROUND-9 ANALYSIS: per block, waves re-read 786 KB of Bprep via L2 for
// only 32 output rows -> 1.2 GB L2 traffic ~ 35 us at L2 ceiling. Fix:
// 64-row blocks (B bytes/output halved), K staged in two 384-wide phases
// in the same 48 KB LDS; per-wave tile/registers unchanged from round 8.

// ============================================================
// Prepass W: [8][64][768] fp32 -> bf16 B-fragments; bias permuted to n-order.
// ============================================================
__global__ __launch_bounds__(256) void prep_w(
    const float* __restrict__ Wi, const float* __restrict__ Wc, const float* __restrict__ Wd,
    const float* __restrict__ bi, const float* __restrict__ bc, const float* __restrict__ bd,
    uintx4* __restrict__ Bprep, float* __restrict__ biasPrep) {
  const int t = blockIdx.x * 256 + threadIdx.x;  // 0 .. 147455
  const int l = t & 63;
  const int frag = t >> 6;             // 0 .. 2303
  const int nt = frag & 3;
  const int q = frag >> 2;
  const int ks = q % 24;
  const int q2 = q / 24;
  const int h = q2 & 7;
  const int mod = q2 >> 3;
  const int n16 = h * 4 + nt;
  const float* __restrict__ W = (mod == 0) ? Wi : ((mod == 1) ? Wc : Wd);

  const int n = n16 * 16 + (l & 15);
  const int r = n >> 3;
  const int c = n & 7;
  const int i0 = ks * 32 + (l >> 4) * 8;
  const float* src = W + (size_t)(c * 64 + r) * 768 + i0;
  floatx4 f0 = *(const floatx4*)(src);
  floatx4 f1 = *(const floatx4*)(src + 4);
  uintx4 p;
  p.x = pk_bf16(f0.x, f0.y);
  p.y = pk_bf16(f0.z, f0.w);
  p.z = pk_bf16(f1.x, f1.y);
  p.w = pk_bf16(f1.z, f1.w);
  Bprep[(size_t)frag * 64 + l] = p;

  if (t < 1536) {
    const int m2 = t >> 9;
    const int nn = t & 511;
    const float* bb = (m2 == 0) ? bi : ((m2 == 1) ? bc : bd);
    biasPrep[t] = bb[(nn & 7) * 64 + (nn >> 3)];
  }
}

// ============================================================
// Fused GEMM + squash, 64-row blocks.
//   Block: 1024 thr / 16 waves (2 row-halves x 8 col-groups); wave owns
//   32x64 (acc[2][4] = 32 AGPR, ~76 regs total -> 16 waves/CU band).
//   A staged per K-phase: 64 rows x 384 cols bf16 frags in 48 KB LDS
//   (slot-XOR swizzled), two phases, 3 barriers; acc carries across.
//   B per block unchanged (786 KB L2) but amortized over 64 rows ->
//   total B L2 traffic halves vs round 8.
//   Grid 768 = 3 mods x 256 m-tiles (XCD swizzle 8x96).
// ============================================================
#define STAGE(p)                                                             \
  {                                                                          \
    _Pragma("unroll") for (int i = 0; i < 6; ++i) {                          \
      const int idx = i * 4096 + tid * 4;        /* flat in 64x384 tile */   \
      const int m = (unsigned)idx / 384u;                                    \
      const int k = idx - m * 384;                                           \
      floatx4 f = *(const floatx4*)(srcbase + (size_t)m * 768 + (p)*384 + k);\
      const int ks = k >> 5;                     /* local K-step 0..11 */    \
      const int kk = k & 31;                                                 \
      const int qk = kk >> 3;                                                \
      const int jh = (kk >> 2) & 1;                                          \
      const int mtg = m >> 4;                    /* 16-row group 0..3 */     \
      const int lnn = m & 15;                                                \
      const int px = (ks * 4 + qk) & 15;         /* slot-XOR spread */       \
      const int slot = (lnn ^ px) + (qk << 4);                               \
      unsigned long long w =                                                 \
          ((unsigned long long)pk_bf16(f.z, f.w) << 32) | pk_bf16(f.x, f.y); \
      As64[(((ks * 4 + mtg) * 64 + slot) << 1) + jh] = w;                    \
    }                                                                        \
  }

#define LOADA(aa, kk) /* kk = LOCAL K-step 0..11 */                          \
  {                                                                          \
    _Pragma("unroll") for (int mt = 0; mt < 2; ++mt)                         \
        aa[mt] = Afr[((kk) * 4 + wr2 + mt) * 64 +                            \
                     ((ln ^ (((kk) * 4 + quad) & 15)) + (quad << 4))];       \
  }

#define LOADB(bb, kk) /* kk = GLOBAL K-step 0..23 */                         \
  {                                                                          \
    _Pragma("unroll") for (int n2 = 0; n2 < 4; ++n2)                         \
        bb[n2] = bbase[(size_t)((kk) * 4 + n2) * 64];                        \
  }

#define COMP(aa, bb)                                                     \
  {                                                                      \
    _Pragma("unroll") for (int mt = 0; mt < 2; ++mt)                     \
    {                                                                    \
      short8 af = __builtin_bit_cast(short8, aa[mt]);                    \
      _Pragma("unroll") for (int n2 = 0; n2 < 4; ++n2)                   \
          acc[mt][n2] = __builtin_amdgcn_mfma_f32_16x16x32_bf16(         \
              af, __builtin_bit_cast(short8, bb[n2]), acc[mt][n2], 0, 0, \
              0);                                                        \
    }                                                                    \
  }

__global__ __launch_bounds__(1024, 4) void caps_fused(
    const float* __restrict__ x0, const float* __restrict__ x1, const float* __restrict__ x2,
    const uintx4* __restrict__ Bprep, const float* __restrict__ biasPrep,
    float* __restrict__ out) {
  __shared__ unsigned long long As64[48 * 128];  // 48 frags x 64 slots x 16 B

  const int tid = threadIdx.x;
  // XCD-chunk swizzle: 768 = 8 XCDs x 96 contiguous blocks (bijective).
  const int bx0 = blockIdx.x;
  const int bx = (bx0 & 7) * 96 + (bx0 >> 3);
  const int mod = bx >> 8;           // 768 = 3 x 256
  const int bm = bx & 255;           // m-tile (64 rows)
  const float* __restrict__ X = (mod == 0) ? x0 : ((mod == 1) ? x1 : x2);
  const float* srcbase = X + (size_t)bm * 64 * 768;

  const int lane = tid & 63;
  const int ln = lane & 15;
  const int quad = lane >> 4;
  const int wv = tid >> 6;           // 0..15
  const int wr = wv >> 3;            // row-half 0..1
  const int wc = wv & 7;             // col-group (h) 0..7
  const int wr2 = wr << 1;

  const uintx4* Afr = (const uintx4*)As64;
  const uintx4* bbase = Bprep + (size_t)(mod * 8 + wc) * (96 * 64) + lane;

  floatx4 acc[2][4] = {};
  uintx4 a0[2], a1[2], b0[4], b1[4];

  // ---- phase 0: stage rows 0..63 x K 0..383 ----
  STAGE(0);
  __syncthreads();
  LOADA(a0, 0);
  LOADB(b0, 0);
#pragma unroll 1
  for (int it = 0; it < 6; ++it) {
    const int s = 2 * it;
    LOADA(a1, s + 1); LOADB(b1, s + 1);
    COMP(a0, b0);
    if (it != 5) { LOADA(a0, s + 2); LOADB(b0, s + 2); }
    COMP(a1, b1);
  }
  // ---- phase 1: restage K 384..767; prefetch its first B over the stage ----
  LOADB(b0, 12);        // global, no LDS dependency
  __syncthreads();      // WAR: phase-0 ds_reads complete before overwrite
  STAGE(1);
  __syncthreads();
  LOADA(a0, 0);
#pragma unroll 1
  for (int it = 0; it < 6; ++it) {
    const int s = 2 * it;
    LOADA(a1, s + 1); LOADB(b1, 12 + s + 1);
    COMP(a0, b0);
    if (it != 5) { LOADA(a0, s + 2); LOADB(b0, 12 + s + 2); }
    COMP(a1, b1);
  }

  // ---- epilogue: bias + squash (8 capsule lanes share s) + store ----
  const int col0 = mod * 512 + wc * 64 + ln;
  float bias[4];
#pragma unroll
  for (int n2 = 0; n2 < 4; ++n2) bias[n2] = biasPrep[col0 + n2 * 16];

#pragma unroll
  for (int mt = 0; mt < 2; ++mt) {
    const size_t rbase = (size_t)(bm * 64 + wr * 32 + mt * 16 + quad * 4) * 1536;
#pragma unroll
    for (int n2 = 0; n2 < 4; ++n2) {
      float* op = out + rbase + col0 + n2 * 16;
#pragma unroll
      for (int jj = 0; jj < 4; ++jj) {
        float u = acc[mt][n2][jj] + bias[n2];
        float s = u * u;
        s += __shfl_xor(s, 1);
        s += __shfl_xor(s, 2);
        s += __shfl_xor(s, 4);
#if __has_builtin(__builtin_amdgcn_rsqf) && __has_builtin(__builtin_amdgcn_rcpf)
        float sc = s * __builtin_amdgcn_rsqf(s + 1e-7f) *
                   __builtin_amdgcn_rcpf(1.0f + s);
#else
        float sc = s / ((1.0f + s) * sqrtf(s + 1e-7f));
#endif
        op[(size_t)jj * 1536] = u * sc;
      }
    }
  }
}

// ============================================================
extern "C" void kernel_launch(void* const* d_in, const int* in_sizes, int n_in,
                              void* d_out, int out_size, void* d_ws, size_t ws_size,
                              hipStream_t stream) {
  const float* ximg = (const float*)d_in[0];
  const float* xcapt = (const float*)d_in[1];
  const float* xdct = (const float*)d_in[2];
  const float* Wi = (const float*)d_in[3];
  const float* bi = (const float*)d_in[4];
  const float* Wc = (const float*)d_in[5];
  const float* bc = (const float*)d_in[6];
  const float* Wd = (const float*)d_in[7];
  const float* bd = (const float*)d_in[8];

  uintx4* Bprep = (uintx4*)d_ws;                           // 2.25 MiB
  float* biasPrep = (float*)((char*)d_ws + 2304 * 1024);   // 6 KiB

  hipLaunchKernelGGL(prep_w, dim3(576), dim3(256), 0, stream,
                     Wi, Wc, Wd, bi, bc, bd, Bprep, biasPrep);
  hipLaunchKernelGGL(caps_fused, dim3(768), dim3(1024), 0, stream,
                     ximg, xcapt, xdct, (const uintx4*)Bprep, biasPrep,
                     (float*)d_out);
}

// Round 10
// 83.063 us; speedup vs baseline: 1.0896x; 1.0896x over previous
//
#include <hip/hip_runtime.h>

// ---------- types ----------
typedef __attribute__((ext_vector_type(8))) short short8;     // 8 bf16 (4 VGPRs)
typedef __attribute__((ext_vector_type(4))) float floatx4;    // MFMA C/D
typedef __attribute__((ext_vector_type(4))) unsigned int uintx4;

// ---------- fp32 -> packed bf16x2 (RNE) ----------
#if __has_builtin(__builtin_amdgcn_cvt_pk_bf16_f32)
typedef __attribute__((ext_vector_type(2))) __bf16 bf16x2;
__device__ __forceinline__ unsigned int pk_bf16(float a, float b) {
  bf16x2 v = __builtin_amdgcn_cvt_pk_bf16_f32(a, b);
  return __builtin_bit_cast(unsigned int, v);
}
#else
__device__ __forceinline__ unsigned int bf16_1(float f) {
  unsigned int u = __builtin_bit_cast(unsigned int, f);
  return (u + 0x7fffu + ((u >> 16) & 1u)) >> 16;
}
__device__ __forceinline__ unsigned int pk_bf16(float a, float b) {
  return bf16_1(a) | (bf16_1(b) << 16);
}
#endif

// Fragment conventions (verified rounds 0-9, absmax 3.9e-3):
//   A-frag (16x16x32): lane(ln,quad) holds A[m=ln][k=quad*8+j], j=0..7
//   B-frag:            lane(ln,quad) holds B[n=ln][k=quad*8+j]  (B[k][n]=W[c][r][k], n=r*8+c)
//   C/D:               col=ln, row=quad*4+reg
// Bprep frag id: Fb = ((mod*8 + h)*24 + ks)*4 + nt, n16 = h*4+nt; frag = 64 lanes x 16B.
//
// LEDGER OF DEAD ENDS (do not revisit without new evidence):
// * STORE GEOMETRY IS LOAD-BEARING: scalar dword stores, 16 consecutive
//   dwords per 16-lane group x 4 rows per instr -> WRITE_SIZE 98.5 MB (1.0x).
//   float4 @32B-stride = 1.5x; LDS-bounced dense dwordx4 = 3.0x, NT or not;
//   extra writes also evict X from L3 (FETCH 81->127 MB).
// * NONTEMPORAL hints: loads defeat L3 residency of X, stores amplify writes.
// * PERMUTED-B (n'=c*64+r) + direct stores: silent transpose (round-6).
// * 3-DEEP REGISTER BUFFERING at 8-frag wave width: spills; signature is
//   WRITE_SIZE 612 MB / FETCH 211 MB / 2.4x dur (round 7).
// * 64-ROW BLOCKS (B-traffic halving): B L2 bandwidth is NOT binding
//   (round 9: -8 us predicted, +8 us actual). Amortization trades that
//   worsen occupancy/quantization lose; waves/CU is what correlates with
//   performance (rounds 5->8->9).

// ============================================================
// Prepass W: [8][64][768] fp32 -> bf16 B-fragments; bias permuted to n-order.
// ============================================================
__global__ __launch_bounds__(256) void prep_w(
    const float* __restrict__ Wi, const float* __restrict__ Wc, const float* __restrict__ Wd,
    const float* __restrict__ bi, const float* __restrict__ bc, const float* __restrict__ bd,
    uintx4* __restrict__ Bprep, float* __restrict__ biasPrep) {
  const int t = blockIdx.x * 256 + threadIdx.x;  // 0 .. 147455
  const int l = t & 63;
  const int frag = t >> 6;             // 0 .. 2303
  const int nt = frag & 3;
  const int q = frag >> 2;
  const int ks = q % 24;
  const int q2 = q / 24;
  const int h = q2 & 7;
  const int mod = q2 >> 3;
  const int n16 = h * 4 + nt;
  const float* __restrict__ W = (mod == 0) ? Wi : ((mod == 1) ? Wc : Wd);

  const int n = n16 * 16 + (l & 15);
  const int r = n >> 3;
  const int c = n & 7;
  const int i0 = ks * 32 + (l >> 4) * 8;
  const float* src = W + (size_t)(c * 64 + r) * 768 + i0;
  floatx4 f0 = *(const floatx4*)(src);
  floatx4 f1 = *(const floatx4*)(src + 4);
  uintx4 p;
  p.x = pk_bf16(f0.x, f0.y);
  p.y = pk_bf16(f0.z, f0.w);
  p.z = pk_bf16(f1.x, f1.y);
  p.w = pk_bf16(f1.z, f1.w);
  Bprep[(size_t)frag * 64 + l] = p;

  if (t < 1536) {
    const int m2 = t >> 9;
    const int nn = t & 511;
    const float* bb = (m2 == 0) ? bi : ((m2 == 1) ? bc : bd);
    biasPrep[t] = bb[(nn & 7) * 64 + (nn >> 3)];
  }
}

// ============================================================
// Fused GEMM + squash, max-occupancy tiling.
//   Block: 1024 thr / 16 waves; wave owns 32x32 (acc[2][2] = 16 AGPR,
//   a-dbuf 16 + b-dbuf 16 + addr ~14 -> ~62 regs). launch_bounds(1024,8)
//   caps at 64 regs -> 2 blocks/CU = 32 waves/CU (100% wave occupancy).
//   A (32 x 768) staged ONCE by 1024 thr into 48 KB LDS (slot-XOR),
//   one barrier, barrier-free 24-step K-loop (2 ds_read_b128 + 2 B loads
//   + 4 MFMA per step, 2-deep). Latency cover from 8 waves/SIMD TLP.
//   Grid 1536 = 3 mods x 512 m-tiles (XCD swizzle 8x192; 6 blocks/CU
//   lifetime = clean 3 rounds of 2 co-resident).
//   Epilogue/store geometry: proven 1.0x pattern, unchanged.
// ============================================================
#define LOADA(aa, kk)                                                        \
  {                                                                          \
    _Pragma("unroll") for (int mt = 0; mt < 2; ++mt)                         \
        aa[mt] = Afr[((kk) * 2 + mt) * 64 +                                  \
                     ((ln ^ (((kk) * 4 + quad) & 15)) + (quad << 4))];       \
  }

#define LOADB(bb, kk)                                                        \
  {                                                                          \
    _Pragma("unroll") for (int n2 = 0; n2 < 2; ++n2)                         \
        bb[n2] = bbase[(size_t)((kk) * 4 + nt0 + n2) * 64];                  \
  }

#define COMP(aa, bb)                                                     \
  {                                                                      \
    _Pragma("unroll") for (int mt = 0; mt < 2; ++mt)                     \
    {                                                                    \
      short8 af = __builtin_bit_cast(short8, aa[mt]);                    \
      _Pragma("unroll") for (int n2 = 0; n2 < 2; ++n2)                   \
          acc[mt][n2] = __builtin_amdgcn_mfma_f32_16x16x32_bf16(         \
              af, __builtin_bit_cast(short8, bb[n2]), acc[mt][n2], 0, 0, \
              0);                                                        \
    }                                                                    \
  }

__global__ __launch_bounds__(1024, 8) void caps_fused(
    const float* __restrict__ x0, const float* __restrict__ x1, const float* __restrict__ x2,
    const uintx4* __restrict__ Bprep, const float* __restrict__ biasPrep,
    float* __restrict__ out) {
  __shared__ unsigned long long As64[48 * 128];  // 48 frags x 64 slots x 16 B

  const int tid = threadIdx.x;
  // XCD-chunk swizzle: 1536 = 8 XCDs x 192 contiguous blocks (bijective).
  const int bx0 = blockIdx.x;
  const int bx = (bx0 & 7) * 192 + (bx0 >> 3);
  const int mod = bx >> 9;           // 1536 = 3 x 512
  const int bm = bx & 511;           // m-tile (32 rows)
  const float* __restrict__ X = (mod == 0) ? x0 : ((mod == 1) ? x1 : x2);

  // ---- one-shot staging: 32 rows x 768 cols fp32, coalesced, 1024 thr ----
  const float* src = X + (size_t)bm * 32 * 768;
#pragma unroll
  for (int i = 0; i < 6; ++i) {
    const int idx = i * 4096 + tid * 4;          // flat float index in tile
    floatx4 f = *(const floatx4*)(src + idx);
    const int m = (unsigned)idx / 768u;
    const int k = idx - m * 768;
    const int ks = k >> 5;
    const int kk = k & 31;
    const int qk = kk >> 3;                      // quad of k
    const int jh = (kk >> 2) & 1;                // which 8-byte half
    const int mt = m >> 4;
    const int lnn = m & 15;
    const int p = (ks * 4 + qk) & 15;            // slot-XOR spread
    const int slot = (lnn ^ p) + (qk << 4);
    unsigned long long w =
        ((unsigned long long)pk_bf16(f.z, f.w) << 32) | pk_bf16(f.x, f.y);
    As64[(((ks * 2 + mt) * 64 + slot) << 1) + jh] = w;
  }
  __syncthreads();  // the ONLY barrier

  const int lane = tid & 63;
  const int ln = lane & 15;
  const int quad = lane >> 4;
  const int wv = tid >> 6;           // 0..15: col-group, n16 = wv*2 .. wv*2+1
  const int nt0 = (wv & 1) * 2;      // nt offset within h-group

  const uintx4* Afr = (const uintx4*)As64;
  const uintx4* bbase = Bprep + (size_t)(mod * 8 + (wv >> 1)) * (96 * 64) + lane;

  floatx4 acc[2][2] = {};
  uintx4 a0[2], a1[2], b0[2], b1[2];

  LOADA(a0, 0);
  LOADB(b0, 0);
#pragma unroll 1
  for (int ks2 = 0; ks2 < 12; ++ks2) {
    const int ks = 2 * ks2;
    LOADA(a1, ks + 1);
    LOADB(b1, ks + 1);
    COMP(a0, b0);
    if (ks2 != 11) {
      LOADA(a0, ks + 2);
      LOADB(b0, ks + 2);
    }
    COMP(a1, b1);
  }

  // ---- epilogue: bias + squash (8 capsule lanes share s) + store ----
  const int col0 = mod * 512 + wv * 32 + ln;
  float bias[2];
#pragma unroll
  for (int n2 = 0; n2 < 2; ++n2) bias[n2] = biasPrep[col0 + n2 * 16];

#pragma unroll
  for (int mt = 0; mt < 2; ++mt) {
    const size_t rbase = (size_t)(bm * 32 + mt * 16 + quad * 4) * 1536;
#pragma unroll
    for (int n2 = 0; n2 < 2; ++n2) {
      float* op = out + rbase + col0 + n2 * 16;
#pragma unroll
      for (int jj = 0; jj < 4; ++jj) {
        float u = acc[mt][n2][jj] + bias[n2];
        float s = u * u;
        s += __shfl_xor(s, 1);
        s += __shfl_xor(s, 2);
        s += __shfl_xor(s, 4);
#if __has_builtin(__builtin_amdgcn_rsqf) && __has_builtin(__builtin_amdgcn_rcpf)
        float sc = s * __builtin_amdgcn_rsqf(s + 1e-7f) *
                   __builtin_amdgcn_rcpf(1.0f + s);
#else
        float sc = s / ((1.0f + s) * sqrtf(s + 1e-7f));
#endif
        op[(size_t)jj * 1536] = u * sc;
      }
    }
  }
}

// ============================================================
extern "C" void kernel_launch(void* const* d_in, const int* in_sizes, int n_in,
                              void* d_out, int out_size, void* d_ws, size_t ws_size,
                              hipStream_t stream) {
  const float* ximg = (const float*)d_in[0];
  const float* xcapt = (const float*)d_in[1];
  const float* xdct = (const float*)d_in[2];
  const float* Wi = (const float*)d_in[3];
  const float* bi = (const float*)d_in[4];
  const float* Wc = (const float*)d_in[5];
  const float* bc = (const float*)d_in[6];
  const float* Wd = (const float*)d_in[7];
  const float* bd = (const float*)d_in[8];

  uintx4* Bprep = (uintx4*)d_ws;                           // 2.25 MiB
  float* biasPrep = (float*)((char*)d_ws + 2304 * 1024);   // 6 KiB

  hipLaunchKernelGGL(prep_w, dim3(576), dim3(256), 0, stream,
                     Wi, Wc, Wd, bi, bc, bd, Bprep, biasPrep);
  hipLaunchKernelGGL(caps_fused, dim3(1536), dim3(1024), 0, stream,
                     ximg, xcapt, xdct, (const uintx4*)Bprep, biasPrep,
                     (float*)d_out);
}

// Round 11
// 81.427 us; speedup vs baseline: 1.1114x; 1.0201x over previous
//
#include <hip/hip_runtime.h>

// ---------- types ----------
typedef __attribute__((ext_vector_type(8))) short short8;     // 8 bf16 (4 VGPRs)
typedef __attribute__((ext_vector_type(4))) float floatx4;    // MFMA C/D
typedef __attribute__((ext_vector_type(4))) unsigned int uintx4;

// ---------- fp32 -> packed bf16x2 (RNE) ----------
#if __has_builtin(__builtin_amdgcn_cvt_pk_bf16_f32)
typedef __attribute__((ext_vector_type(2))) __bf16 bf16x2;
__device__ __forceinline__ unsigned int pk_bf16(float a, float b) {
  bf16x2 v = __builtin_amdgcn_cvt_pk_bf16_f32(a, b);
  return __builtin_bit_cast(unsigned int, v);
}
#else
__device__ __forceinline__ unsigned int bf16_1(float f) {
  unsigned int u = __builtin_bit_cast(unsigned int, f);
  return (u + 0x7fffu + ((u >> 16) & 1u)) >> 16;
}
__device__ __forceinline__ unsigned int pk_bf16(float a, float b) {
  return bf16_1(a) | (bf16_1(b) << 16);
}
#endif

// Fragment conventions (verified rounds 0-10, absmax 3.9e-3):
//   A-frag (16x16x32): lane(ln,quad) holds A[m=ln][k=quad*8+j], j=0..7
//   B-frag:            lane(ln,quad) holds B[n=ln][k=quad*8+j]  (B[k][n]=W[c][r][k], n=r*8+c)
//   C/D:               col=ln, row=quad*4+reg
// Bprep frag id: Fb = ((mod*8 + h)*24 + ks)*4 + nt, n16 = h*4+nt; frag = 64 lanes x 16B.
//
// LEDGER OF DEAD ENDS (do not revisit without new evidence):
// * STORE GEOMETRY IS LOAD-BEARING: scalar dword stores, 16 consecutive
//   dwords per 16-lane group x 4 rows per instr -> WRITE_SIZE 98.5 MB (1.0x).
//   float4 @32B-stride = 1.5x; LDS-bounced dense dwordx4 = 3.0x, NT or not;
//   extra writes also evict X from L3 (FETCH 81->127 MB).
// * NONTEMPORAL hints: loads defeat L3 residency of X, stores amplify writes.
// * PERMUTED-B (n'=c*64+r) + direct stores: silent transpose (round-6).
// * 3-DEEP BUFFERING AT WIDTH-8 / 256-thr (256,3): ~190 regs > 170 cap ->
//   spill signature WRITE 612 MB / FETCH 211 MB / 2.4x dur (round 7).
//   Width-4 at (512,4) has headroom: 76 of 128 used (round 8).
// * 64-ROW BLOCKS (B-traffic halving): B L2 bandwidth NOT binding (round 9).
// * OCCUPANCY 43% -> 76% (round 10, 32x32 waves): ZERO effect on duration.
//   TLP beyond ~14 waves/CU doesn't help; remaining stall is per-wave
//   dependency chain -> attack with prefetch DEPTH, not more waves.

// ============================================================
// Prepass W: [8][64][768] fp32 -> bf16 B-fragments; bias permuted to n-order.
// ============================================================
__global__ __launch_bounds__(256) void prep_w(
    const float* __restrict__ Wi, const float* __restrict__ Wc, const float* __restrict__ Wd,
    const float* __restrict__ bi, const float* __restrict__ bc, const float* __restrict__ bd,
    uintx4* __restrict__ Bprep, float* __restrict__ biasPrep) {
  const int t = blockIdx.x * 256 + threadIdx.x;  // 0 .. 147455
  const int l = t & 63;
  const int frag = t >> 6;             // 0 .. 2303
  const int nt = frag & 3;
  const int q = frag >> 2;
  const int ks = q % 24;
  const int q2 = q / 24;
  const int h = q2 & 7;
  const int mod = q2 >> 3;
  const int n16 = h * 4 + nt;
  const float* __restrict__ W = (mod == 0) ? Wi : ((mod == 1) ? Wc : Wd);

  const int n = n16 * 16 + (l & 15);
  const int r = n >> 3;
  const int c = n & 7;
  const int i0 = ks * 32 + (l >> 4) * 8;
  const float* src = W + (size_t)(c * 64 + r) * 768 + i0;
  floatx4 f0 = *(const floatx4*)(src);
  floatx4 f1 = *(const floatx4*)(src + 4);
  uintx4 p;
  p.x = pk_bf16(f0.x, f0.y);
  p.y = pk_bf16(f0.z, f0.w);
  p.z = pk_bf16(f1.x, f1.y);
  p.w = pk_bf16(f1.z, f1.w);
  Bprep[(size_t)frag * 64 + l] = p;

  if (t < 1536) {
    const int m2 = t >> 9;
    const int nn = t & 511;
    const float* bb = (m2 == 0) ? bi : ((m2 == 1) ? bc : bd);
    biasPrep[t] = bb[(nn & 7) * 64 + (nn >> 3)];
  }
}

// ============================================================
// Fused GEMM + squash. ROUND-11 = round-8 kernel (82.4 us verified) with
// THREE-deep register prefetch (a0/a1/a2, b0/b1/b2): each buffer's loads
// issue two full COMP phases before use (~2x issue-slot latency cover).
// Width-4 wave tile keeps regs ~100 of the 128 cap at (512,4) -> no spill.
//   Block: 512 thr / 8 waves; wave owns 32x64 (acc[2][4] = 32 AGPR).
//   A (32x768) staged once as bf16 frags in 48 KB LDS (slot-XOR), one
//   barrier, 24-step K-loop as 7x3 pipelined + 3-step drain.
//   Epilogue: shuffle-squash + fast rsq/rcp + proven 1.0x store geometry.
//   Grid 1536 = 3 mods x 512 m-tiles (XCD swizzle 8x192).
// ============================================================
#define LOADA(aa, kk)                                                        \
  {                                                                          \
    _Pragma("unroll") for (int mt = 0; mt < 2; ++mt)                         \
        aa[mt] = Afr[((kk) * 2 + mt) * 64 +                                  \
                     ((ln ^ (((kk) * 4 + quad) & 15)) + (quad << 4))];       \
  }

#define LOADB(bb, kk)                                                        \
  {                                                                          \
    _Pragma("unroll") for (int n2 = 0; n2 < 4; ++n2)                         \
        bb[n2] = bbase[(size_t)((kk) * 4 + n2) * 64];                        \
  }

#define COMP(aa, bb)                                                     \
  {                                                                      \
    _Pragma("unroll") for (int mt = 0; mt < 2; ++mt)                     \
    {                                                                    \
      short8 af = __builtin_bit_cast(short8, aa[mt]);                    \
      _Pragma("unroll") for (int n2 = 0; n2 < 4; ++n2)                   \
          acc[mt][n2] = __builtin_amdgcn_mfma_f32_16x16x32_bf16(         \
              af, __builtin_bit_cast(short8, bb[n2]), acc[mt][n2], 0, 0, \
              0);                                                        \
    }                                                                    \
  }

__global__ __launch_bounds__(512, 4) void caps_fused(
    const float* __restrict__ x0, const float* __restrict__ x1, const float* __restrict__ x2,
    const uintx4* __restrict__ Bprep, const float* __restrict__ biasPrep,
    float* __restrict__ out) {
  __shared__ unsigned long long As64[48 * 128];  // 48 frags x 64 slots x 16 B

  const int tid = threadIdx.x;
  // XCD-chunk swizzle: 1536 = 8 XCDs x 192 contiguous blocks (bijective).
  const int bx0 = blockIdx.x;
  const int bx = (bx0 & 7) * 192 + (bx0 >> 3);
  const int mod = bx >> 9;           // 1536 = 3 x 512
  const int bm = bx & 511;           // m-tile (32 rows)
  const float* __restrict__ X = (mod == 0) ? x0 : ((mod == 1) ? x1 : x2);

  // ---- one-shot staging: 32 rows x 768 cols fp32, coalesced, 512 thr ----
  const float* src = X + (size_t)bm * 32 * 768;
#pragma unroll
  for (int i = 0; i < 12; ++i) {
    const int idx = i * 2048 + tid * 4;          // flat float index in tile
    floatx4 f = *(const floatx4*)(src + idx);
    const int m = (unsigned)idx / 768u;
    const int k = idx - m * 768;
    const int ks = k >> 5;
    const int kk = k & 31;
    const int qk = kk >> 3;                      // quad of k
    const int jh = (kk >> 2) & 1;                // which 8-byte half
    const int mt = m >> 4;
    const int lnn = m & 15;
    const int p = (ks * 4 + qk) & 15;            // slot-XOR spread
    const int slot = (lnn ^ p) + (qk << 4);
    unsigned long long w =
        ((unsigned long long)pk_bf16(f.z, f.w) << 32) | pk_bf16(f.x, f.y);
    As64[(((ks * 2 + mt) * 64 + slot) << 1) + jh] = w;
  }
  __syncthreads();  // the ONLY barrier

  const int lane = tid & 63;
  const int ln = lane & 15;
  const int quad = lane >> 4;
  const int wv = tid >> 6;  // wave id 0..7 == h: n16-range wv*4 .. wv*4+3

  const uintx4* Afr = (const uintx4*)As64;
  const uintx4* bbase = Bprep + (size_t)(mod * 8 + wv) * (96 * 64) + lane;

  floatx4 acc[2][4] = {};
  uintx4 a0[2], a1[2], a2[2], b0[4], b1[4], b2[4];

  LOADA(a0, 0); LOADB(b0, 0);
  LOADA(a1, 1); LOADB(b1, 1);
  LOADA(a2, 2); LOADB(b2, 2);
#pragma unroll 1
  for (int it = 0; it < 7; ++it) {
    const int s = 3 * it;
    COMP(a0, b0);
    LOADA(a0, s + 3); LOADB(b0, s + 3);
    COMP(a1, b1);
    LOADA(a1, s + 4); LOADB(b1, s + 4);
    COMP(a2, b2);
    LOADA(a2, s + 5); LOADB(b2, s + 5);
  }
  COMP(a0, b0);   // step 21
  COMP(a1, b1);   // step 22
  COMP(a2, b2);   // step 23

  // ---- epilogue: bias + squash (8 capsule lanes share s) + store ----
  const int col0 = mod * 512 + wv * 64 + ln;
  float bias[4];
#pragma unroll
  for (int n2 = 0; n2 < 4; ++n2) bias[n2] = biasPrep[col0 + n2 * 16];

#pragma unroll
  for (int mt = 0; mt < 2; ++mt) {
    const size_t rbase = (size_t)(bm * 32 + mt * 16 + quad * 4) * 1536;
#pragma unroll
    for (int n2 = 0; n2 < 4; ++n2) {
      float* op = out + rbase + col0 + n2 * 16;
#pragma unroll
      for (int jj = 0; jj < 4; ++jj) {
        float u = acc[mt][n2][jj] + bias[n2];
        float s = u * u;
        s += __shfl_xor(s, 1);
        s += __shfl_xor(s, 2);
        s += __shfl_xor(s, 4);
#if __has_builtin(__builtin_amdgcn_rsqf) && __has_builtin(__builtin_amdgcn_rcpf)
        float sc = s * __builtin_amdgcn_rsqf(s + 1e-7f) *
                   __builtin_amdgcn_rcpf(1.0f + s);
#else
        float sc = s / ((1.0f + s) * sqrtf(s + 1e-7f));
#endif
        op[(size_t)jj * 1536] = u * sc;
      }
    }
  }
}

// ============================================================
extern "C" void kernel_launch(void* const* d_in, const int* in_sizes, int n_in,
                              void* d_out, int out_size, void* d_ws, size_t ws_size,
                              hipStream_t stream) {
  const float* ximg = (const float*)d_in[0];
  const float* xcapt = (const float*)d_in[1];
  const float* xdct = (const float*)d_in[2];
  const float* Wi = (const float*)d_in[3];
  const float* bi = (const float*)d_in[4];
  const float* Wc = (const float*)d_in[5];
  const float* bc = (const float*)d_in[6];
  const float* Wd = (const float*)d_in[7];
  const float* bd = (const float*)d_in[8];

  uintx4* Bprep = (uintx4*)d_ws;                           // 2.25 MiB
  float* biasPrep = (float*)((char*)d_ws + 2304 * 1024);   // 6 KiB

  hipLaunchKernelGGL(prep_w, dim3(576), dim3(256), 0, stream,
                     Wi, Wc, Wd, bi, bc, bd, Bprep, biasPrep);
  hipLaunchKernelGGL(caps_fused, dim3(1536), dim3(512), 0, stream,
                     ximg, xcapt, xdct, (const uintx4*)Bprep, biasPrep,
                     (float*)d_out);
}